// Round 5
// baseline (184.903 us; speedup 1.0000x reference)
//
#include <hip/hip_runtime.h>
#include <hip/hip_bf16.h>
#include <hip/hip_fp16.h>

#define LQ     12240

typedef _Float16 half8 __attribute__((ext_vector_type(8)));
typedef float floatx4 __attribute__((ext_vector_type(4)));
typedef unsigned int uint;

// ---------------------------------------------------------------------------
// f32 -> f16 elementwise (float4 granularity)
// ---------------------------------------------------------------------------
__global__ __launch_bounds__(256) void cvt_f32_f16(
    const float* __restrict__ in, __half* __restrict__ out, int n4) {
  const int i = blockIdx.x * 256 + threadIdx.x;
  if (i >= n4) return;
  const float4 v = reinterpret_cast<const float4*>(in)[i];
  const __half2 a = __floats2half2_rn(v.x, v.y);
  const __half2 b = __floats2half2_rn(v.z, v.w);
  uint2 pk;
  pk.x = *reinterpret_cast<const uint*>(&a);
  pk.y = *reinterpret_cast<const uint*>(&b);
  reinterpret_cast<uint2*>(out)[i] = pk;
}

// ---------------------------------------------------------------------------
// Weight transpose + cvt: in f32 [256][N] -> out f16 [N][256]
// ---------------------------------------------------------------------------
__global__ __launch_bounds__(256) void transpose_cvt(
    const float* __restrict__ in, __half* __restrict__ out, int N) {
  __shared__ float t[32][33];
  const int n0 = blockIdx.x * 32, k0 = blockIdx.y * 32;
  const int c = threadIdx.x & 31, r = threadIdx.x >> 5;
#pragma unroll
  for (int i = 0; i < 4; ++i)
    t[r + i * 8][c] = in[(size_t)(k0 + r + i * 8) * N + n0 + c];
  __syncthreads();
#pragma unroll
  for (int i = 0; i < 4; ++i)
    out[(size_t)(n0 + r + i * 8) * 256 + k0 + c] = __float2half(t[c][r + i * 8]);
}

// ---------------------------------------------------------------------------
// f16 MFMA GEMM: C[M,N] = A[M,256] @ Bt[N,256]^T + bias[N]  (unchanged r4)
// ---------------------------------------------------------------------------
template <typename TC>
__device__ inline void store_c(TC* C, size_t idx, float v);
template <> __device__ inline void store_c<float>(float* C, size_t idx, float v) { C[idx] = v; }
template <> __device__ inline void store_c<__half>(__half* C, size_t idx, float v) { C[idx] = __float2half(v); }

template <typename TC>
__global__ __launch_bounds__(256) void gemm_mfma(
    const __half* __restrict__ A,    // [M][256]
    const __half* __restrict__ Bt,   // [N][256]
    const float* __restrict__ bias,  // [N]
    TC* __restrict__ C, int M, int N) {
  __shared__ uint4 As_g[128 * 8];
  __shared__ uint4 Bs_g[128 * 8];

  const int tid = threadIdx.x;
  const int bm = blockIdx.y * 128, bn = blockIdx.x * 128;
  const int wid = tid >> 6, lane = tid & 63;
  const int wr = wid >> 1, wn = wid & 1;
  const int l16 = lane & 15, lhi = lane >> 4;

  floatx4 acc[4][4] = {};

  const int srow = tid >> 1;
  const int sg0 = (tid & 1) * 4;
  const bool arow_ok = (bm + srow) < M;
  const __half* Arow = A + (size_t)(arow_ok ? bm + srow : 0) * 256;
  const __half* Brow = Bt + (size_t)(bn + srow) * 256;

  for (int ks = 0; ks < 4; ++ks) {
    const int k0 = ks * 64;
#pragma unroll
    for (int i = 0; i < 4; ++i) {
      const int g = sg0 + i;
      uint4 av = make_uint4(0, 0, 0, 0);
      if (arow_ok) av = *reinterpret_cast<const uint4*>(Arow + k0 + g * 8);
      As_g[srow * 8 + (g ^ (srow & 7))] = av;
      Bs_g[srow * 8 + (g ^ (srow & 7))] =
          *reinterpret_cast<const uint4*>(Brow + k0 + g * 8);
    }
    __syncthreads();

#pragma unroll
    for (int kk = 0; kk < 2; ++kk) {
      half8 a[4], b[4];
#pragma unroll
      for (int m = 0; m < 4; ++m) {
        const int row = wr * 64 + m * 16 + l16;
        const int g = kk * 4 + lhi;
        union { uint4 u; half8 h; } cv;
        cv.u = As_g[row * 8 + (g ^ (row & 7))];
        a[m] = cv.h;
      }
#pragma unroll
      for (int n = 0; n < 4; ++n) {
        const int row = wn * 64 + n * 16 + l16;
        const int g = kk * 4 + lhi;
        union { uint4 u; half8 h; } cv;
        cv.u = Bs_g[row * 8 + (g ^ (row & 7))];
        b[n] = cv.h;
      }
#pragma unroll
      for (int m = 0; m < 4; ++m)
#pragma unroll
        for (int n = 0; n < 4; ++n)
          acc[m][n] = __builtin_amdgcn_mfma_f32_16x16x32_f16(a[m], b[n], acc[m][n], 0, 0, 0);
    }
    __syncthreads();
  }

#pragma unroll
  for (int m = 0; m < 4; ++m) {
    const int row0 = bm + wr * 64 + m * 16 + lhi * 4;
#pragma unroll
    for (int n = 0; n < 4; ++n) {
      const int col = bn + wn * 64 + n * 16 + l16;
      const float bv = bias[col];
#pragma unroll
      for (int r = 0; r < 4; ++r) {
        const int row = row0 + r;
        if (row < M) store_c<TC>(C, (size_t)row * N + col, acc[m][n][r] + bv);
      }
    }
  }
}

// ---------------------------------------------------------------------------
// helpers for packed f16 math
// ---------------------------------------------------------------------------
__device__ inline uint hfma2u(uint a, uint b, uint c) {
  const __half2 ah = *reinterpret_cast<const __half2*>(&a);
  const __half2 bh = *reinterpret_cast<const __half2*>(&b);
  const __half2 ch = *reinterpret_cast<const __half2*>(&c);
  const __half2 r = __hfma2(ah, bh, ch);
  return *reinterpret_cast<const uint*>(&r);
}

// ---------------------------------------------------------------------------
// Fused softmax + location + deformable bilinear sampling, 2 queries / block.
// Phase 1: records (4 f16 combined weights + 4 u32 byte-offsets) -> SoA LDS,
//          reg-staged so the record arrays overlay the logits buffer.
// Phase 2: 8 lanes per (q,h,parity); dword2 value loads; v_perm weight dup;
//          packed __hfma2 accumulation, f32 promotion per level.
// Slot index (qi<<9)|(k<<3)|(h^((k&1)<<2)) is bank-conflict-free for both
// the 64-distinct-granule writes and the 8-broadcast-granule reads.
// ---------------------------------------------------------------------------
__global__ __launch_bounds__(256) void sample_kernel(
    const __half* __restrict__ value,     // (LQ, 256) f16
    const __half* __restrict__ logits,    // (LQ, 512) f16
    const __half* __restrict__ off,       // (LQ, 1024) f16
    const float* __restrict__ tempoff,    // (LQ, 4, 4, 2) f32
    const float* __restrict__ refpts,     // (LQ, 4, 2) f32
    __half* __restrict__ msout) {         // (LQ, 256) f16
  const int q0 = blockIdx.x * 2;
  const int tid = threadIdx.x;

  __shared__ __align__(16) char smem[24576];
  uint4* soff = reinterpret_cast<uint4*>(smem);          // [1024] 16 KB
  uint2* swgt = reinterpret_cast<uint2*>(smem + 16384);  // [1024] 8 KB
  float* slog = reinterpret_cast<float*>(smem);          // [1024] overlay
  __shared__ float sm_m[16], sm_si[16];

  // ---- (a) load logits (2 queries x 512) ----
#pragma unroll
  for (int k = 0; k < 4; ++k) {
    const int s = tid + k * 256;
    slog[s] = __half2float(logits[(size_t)(q0 + (s >> 9)) * 512 + (s & 511)]);
  }
  __syncthreads();

  // ---- (b) per-(query,head) softmax stats: 16 groups x 16 threads ----
  {
    const int g = tid >> 4;
    const int j = tid & 15;
    const float* e = &slog[g * 64];
    float m = fmaxf(fmaxf(e[j], e[j + 16]), fmaxf(e[j + 32], e[j + 48]));
#pragma unroll
    for (int mask = 8; mask >= 1; mask >>= 1) m = fmaxf(m, __shfl_xor(m, mask));
    float s = __expf(e[j] - m) + __expf(e[j + 16] - m) +
              __expf(e[j + 32] - m) + __expf(e[j + 48] - m);
#pragma unroll
    for (int mask = 8; mask >= 1; mask >>= 1) s += __shfl_xor(s, mask);
    if (j == 0) { sm_m[g] = m; sm_si[g] = 1.0f / s; }
  }
  __syncthreads();

  // ---- (c) compute records into registers ----
  const float HWF[4] = {2304.f, 576.f, 144.f, 36.f};
  const float RHW[4] = {1.f / 2304.f, 1.f / 576.f, 1.f / 144.f, 1.f / 36.f};
  const int   S0[4]  = {0, 9216, 11520, 12096};
  const int   HWI[4] = {2304, 576, 144, 36};

  uint4 rec_o[4];
  uint2 rec_w[4];
  int   rec_idx[4];
  const int h1 = (tid >> 3) & 7;
  const int rbase = (tid & 7) | (((tid >> 6) & 3) << 3);

#pragma unroll
  for (int k = 0; k < 4; ++k) {
    const int qi = k & 1;
    const int r  = rbase | ((k >> 1) << 5);
    const int i  = h1 * 64 + r;
    const int l  = r >> 4;
    const int f  = (r >> 2) & 3;
    const size_t q = (size_t)(q0 + qi);
    const int g = (qi << 3) | h1;

    const float w = __expf(slog[(qi << 9) + i] - sm_m[g]) * sm_si[g];

    const float2 o  = __half22float2(*reinterpret_cast<const __half2*>(&off[q * 1024 + i * 2]));
    const float2 to = *reinterpret_cast<const float2*>(&tempoff[q * 32 + (l * 4 + f) * 2]);
    const float2 rp = *reinterpret_cast<const float2*>(&refpts[q * 8 + l * 2]);

    const float hw = HWF[l];
    const float x = (to.x + o.x * 0.25f + rp.x) * 4.0f - 0.5f;
    const float y = (to.y + o.y * RHW[l] + rp.y) * hw - 0.5f;

    const float x0f = floorf(x), y0f = floorf(y);
    const float fx = x - x0f, fy = y - y0f;
    const int x0 = (int)x0f, y0 = (int)y0f;
    const int hl = HWI[l];

    const bool xv0 = (x0 >= 0) && (x0 < 4);
    const bool xv1 = (x0 >= -1) && (x0 < 3);
    const bool yv0 = (y0 >= 0) && (y0 < hl);
    const bool yv1 = (y0 >= -1) && (y0 < hl - 1);
    const int xc0 = min(max(x0, 0), 3);
    const int xc1 = min(max(x0 + 1, 0), 3);
    const int yc0 = min(max(y0, 0), hl - 1);
    const int yc1 = min(max(y0 + 1, 0), hl - 1);

    const float w00 = (xv0 && yv0) ? w * (1.f - fx) * (1.f - fy) : 0.f;
    const float w01 = (xv1 && yv0) ? w * fx * (1.f - fy) : 0.f;
    const float w10 = (xv0 && yv1) ? w * (1.f - fx) * fy : 0.f;
    const float w11 = (xv1 && yv1) ? w * fx * fy : 0.f;

    const int base = S0[l];
    rec_o[k] = make_uint4((uint)(base + yc0 * 4 + xc0) << 9,
                          (uint)(base + yc0 * 4 + xc1) << 9,
                          (uint)(base + yc1 * 4 + xc0) << 9,
                          (uint)(base + yc1 * 4 + xc1) << 9);
    const __half2 p01 = __floats2half2_rn(w00, w01);
    const __half2 p23 = __floats2half2_rn(w10, w11);
    rec_w[k].x = *reinterpret_cast<const uint*>(&p01);
    rec_w[k].y = *reinterpret_cast<const uint*>(&p23);
    rec_idx[k] = (qi << 9) | (r << 3) | (h1 ^ ((r & 1) << 2));
  }
  __syncthreads();   // all slog reads done; record arrays may overlay now

  // ---- (d) write records ----
#pragma unroll
  for (int k = 0; k < 4; ++k) {
    soff[rec_idx[k]] = rec_o[k];
    swgt[rec_idx[k]] = rec_w[k];
  }
  __syncthreads();

  // ---- phase 2: gather + packed FMA ----
  const int qi  = tid >> 7;          // 0..1
  const int h   = (tid >> 4) & 7;    // 0..7
  const int sub = (tid >> 3) & 1;    // sample parity
  const int dl  = tid & 7;           // 4-dim group
  const char* __restrict__ vbase = (const char*)value + h * 64 + dl * 8;

  float f0 = 0.f, f1 = 0.f, f2 = 0.f, f3 = 0.f;

#pragma unroll
  for (int l = 0; l < 4; ++l) {
    uint a01 = 0u, a23 = 0u;   // packed f16 accumulators
#pragma unroll
    for (int tt = 0; tt < 8; ++tt) {
      const int k = l * 16 + tt * 2 + sub;
      const int idx = (qi << 9) | (k << 3) | (h ^ ((k & 1) << 2));
      const uint4 eo = soff[idx];
      const uint2 wg = swgt[idx];
      const uint d00 = __builtin_amdgcn_perm(wg.x, wg.x, 0x01000100u);
      const uint d01 = __builtin_amdgcn_perm(wg.x, wg.x, 0x03020302u);
      const uint d10 = __builtin_amdgcn_perm(wg.y, wg.y, 0x01000100u);
      const uint d11 = __builtin_amdgcn_perm(wg.y, wg.y, 0x03020302u);
      const uint2 v0 = *reinterpret_cast<const uint2*>(vbase + eo.x);
      const uint2 v1 = *reinterpret_cast<const uint2*>(vbase + eo.y);
      const uint2 v2 = *reinterpret_cast<const uint2*>(vbase + eo.z);
      const uint2 v3 = *reinterpret_cast<const uint2*>(vbase + eo.w);
      a01 = hfma2u(d00, v0.x, a01);
      a23 = hfma2u(d00, v0.y, a23);
      a01 = hfma2u(d01, v1.x, a01);
      a23 = hfma2u(d01, v1.y, a23);
      a01 = hfma2u(d10, v2.x, a01);
      a23 = hfma2u(d10, v2.y, a23);
      a01 = hfma2u(d11, v3.x, a01);
      a23 = hfma2u(d11, v3.y, a23);
    }
    const float2 p01 = __half22float2(*reinterpret_cast<const __half2*>(&a01));
    const float2 p23 = __half22float2(*reinterpret_cast<const __half2*>(&a23));
    f0 += p01.x; f1 += p01.y; f2 += p23.x; f3 += p23.y;
  }

  // combine even/odd sample partial sums (lane ^ 8)
  f0 += __shfl_xor(f0, 8);
  f1 += __shfl_xor(f1, 8);
  f2 += __shfl_xor(f2, 8);
  f3 += __shfl_xor(f3, 8);

  if (sub == 0) {
    const __half2 o0 = __floats2half2_rn(f0, f1);
    const __half2 o1 = __floats2half2_rn(f2, f3);
    uint2 st;
    st.x = *reinterpret_cast<const uint*>(&o0);
    st.y = *reinterpret_cast<const uint*>(&o1);
    *reinterpret_cast<uint2*>(&msout[(size_t)(q0 + qi) * 256 + h * 32 + dl * 4]) = st;
  }
}

// ---------------------------------------------------------------------------
extern "C" void kernel_launch(void* const* d_in, const int* in_sizes, int n_in,
                              void* d_out, int out_size, void* d_ws, size_t ws_size,
                              hipStream_t stream) {
  const float* query   = (const float*)d_in[0];
  const float* refpts  = (const float*)d_in[1];
  const float* tempoff = (const float*)d_in[2];
  const float* inflat  = (const float*)d_in[3];
  const float* W_off  = (const float*)d_in[6];
  const float* b_off  = (const float*)d_in[7];
  const float* W_attn = (const float*)d_in[8];
  const float* b_attn = (const float*)d_in[9];
  const float* W_val  = (const float*)d_in[10];
  const float* b_val  = (const float*)d_in[11];
  const float* W_out  = (const float*)d_in[12];
  const float* b_out  = (const float*)d_in[13];

  char* ws = (char*)d_ws;
  const size_t szQ = (size_t)LQ * 256 * 2;
  __half* qh     = (__half*)ws;                 ws += szQ;
  __half* ifh    = (__half*)ws;                 ws += szQ;
  __half* wT_val = (__half*)ws;                 ws += (size_t)256 * 256 * 2;
  __half* wT_att = (__half*)ws;                 ws += (size_t)512 * 256 * 2;
  __half* wT_off = (__half*)ws;                 ws += (size_t)1024 * 256 * 2;
  __half* wT_out = (__half*)ws;                 ws += (size_t)256 * 256 * 2;
  __half* val_h  = (__half*)ws;                 ws += szQ;
  __half* attn_h = (__half*)ws;                 ws += (size_t)LQ * 512 * 2;
  __half* off_h  = (__half*)ws;                 ws += (size_t)LQ * 1024 * 2;
  __half* ms_h   = (__half*)ws;                 ws += szQ;

  const dim3 blk(256);
  const int n4 = LQ * 256 / 4;

  cvt_f32_f16<<<dim3((n4 + 255) / 256), blk, 0, stream>>>(query, qh, n4);
  cvt_f32_f16<<<dim3((n4 + 255) / 256), blk, 0, stream>>>(inflat, ifh, n4);
  transpose_cvt<<<dim3(8, 8),  blk, 0, stream>>>(W_val,  wT_val, 256);
  transpose_cvt<<<dim3(16, 8), blk, 0, stream>>>(W_attn, wT_att, 512);
  transpose_cvt<<<dim3(32, 8), blk, 0, stream>>>(W_off,  wT_off, 1024);
  transpose_cvt<<<dim3(8, 8),  blk, 0, stream>>>(W_out,  wT_out, 256);

  const int gm = (LQ + 127) / 128;  // 96
  gemm_mfma<__half><<<dim3(2, gm), blk, 0, stream>>>(ifh, wT_val, b_val, val_h, LQ, 256);
  gemm_mfma<__half><<<dim3(4, gm), blk, 0, stream>>>(qh, wT_att, b_attn, attn_h, LQ, 512);
  gemm_mfma<__half><<<dim3(8, gm), blk, 0, stream>>>(qh, wT_off, b_off, off_h, LQ, 1024);

  sample_kernel<<<dim3(LQ / 2), blk, 0, stream>>>(val_h, attn_h, off_h, tempoff, refpts, ms_h);

  gemm_mfma<float><<<dim3(2, gm), blk, 0, stream>>>(ms_h, wT_out, b_out, (float*)d_out, LQ, 256);
}

// Round 6
// 144.323 us; speedup vs baseline: 1.2812x; 1.2812x over previous
//
#include <hip/hip_runtime.h>
#include <hip/hip_bf16.h>
#include <hip/hip_fp16.h>

#define LQ     12240

typedef _Float16 half8 __attribute__((ext_vector_type(8)));
typedef float floatx4 __attribute__((ext_vector_type(4)));
typedef unsigned int uint;

// ---------------------------------------------------------------------------
// f32 -> f16 elementwise (float4 granularity)
// ---------------------------------------------------------------------------
__global__ __launch_bounds__(256) void cvt_f32_f16(
    const float* __restrict__ in, __half* __restrict__ out, int n4) {
  const int i = blockIdx.x * 256 + threadIdx.x;
  if (i >= n4) return;
  const float4 v = reinterpret_cast<const float4*>(in)[i];
  const __half2 a = __floats2half2_rn(v.x, v.y);
  const __half2 b = __floats2half2_rn(v.z, v.w);
  uint2 pk;
  pk.x = *reinterpret_cast<const uint*>(&a);
  pk.y = *reinterpret_cast<const uint*>(&b);
  reinterpret_cast<uint2*>(out)[i] = pk;
}

// ---------------------------------------------------------------------------
// Weight transpose + cvt: in f32 [256][N] -> out f16 [N][256]
// ---------------------------------------------------------------------------
__global__ __launch_bounds__(256) void transpose_cvt(
    const float* __restrict__ in, __half* __restrict__ out, int N) {
  __shared__ float t[32][33];
  const int n0 = blockIdx.x * 32, k0 = blockIdx.y * 32;
  const int c = threadIdx.x & 31, r = threadIdx.x >> 5;
#pragma unroll
  for (int i = 0; i < 4; ++i)
    t[r + i * 8][c] = in[(size_t)(k0 + r + i * 8) * N + n0 + c];
  __syncthreads();
#pragma unroll
  for (int i = 0; i < 4; ++i)
    out[(size_t)(n0 + r + i * 8) * 256 + k0 + c] = __float2half(t[c][r + i * 8]);
}

// ---------------------------------------------------------------------------
// f16 MFMA GEMM: C[M,N] = A[M,256] @ Bt[N,256]^T + bias[N]  (unchanged)
// ---------------------------------------------------------------------------
template <typename TC>
__device__ inline void store_c(TC* C, size_t idx, float v);
template <> __device__ inline void store_c<float>(float* C, size_t idx, float v) { C[idx] = v; }
template <> __device__ inline void store_c<__half>(__half* C, size_t idx, float v) { C[idx] = __float2half(v); }

template <typename TC>
__global__ __launch_bounds__(256) void gemm_mfma(
    const __half* __restrict__ A,    // [M][256]
    const __half* __restrict__ Bt,   // [N][256]
    const float* __restrict__ bias,  // [N]
    TC* __restrict__ C, int M, int N) {
  __shared__ uint4 As_g[128 * 8];
  __shared__ uint4 Bs_g[128 * 8];

  const int tid = threadIdx.x;
  const int bm = blockIdx.y * 128, bn = blockIdx.x * 128;
  const int wid = tid >> 6, lane = tid & 63;
  const int wr = wid >> 1, wn = wid & 1;
  const int l16 = lane & 15, lhi = lane >> 4;

  floatx4 acc[4][4] = {};

  const int srow = tid >> 1;
  const int sg0 = (tid & 1) * 4;
  const bool arow_ok = (bm + srow) < M;
  const __half* Arow = A + (size_t)(arow_ok ? bm + srow : 0) * 256;
  const __half* Brow = Bt + (size_t)(bn + srow) * 256;

  for (int ks = 0; ks < 4; ++ks) {
    const int k0 = ks * 64;
#pragma unroll
    for (int i = 0; i < 4; ++i) {
      const int g = sg0 + i;
      uint4 av = make_uint4(0, 0, 0, 0);
      if (arow_ok) av = *reinterpret_cast<const uint4*>(Arow + k0 + g * 8);
      As_g[srow * 8 + (g ^ (srow & 7))] = av;
      Bs_g[srow * 8 + (g ^ (srow & 7))] =
          *reinterpret_cast<const uint4*>(Brow + k0 + g * 8);
    }
    __syncthreads();

#pragma unroll
    for (int kk = 0; kk < 2; ++kk) {
      half8 a[4], b[4];
#pragma unroll
      for (int m = 0; m < 4; ++m) {
        const int row = wr * 64 + m * 16 + l16;
        const int g = kk * 4 + lhi;
        union { uint4 u; half8 h; } cv;
        cv.u = As_g[row * 8 + (g ^ (row & 7))];
        a[m] = cv.h;
      }
#pragma unroll
      for (int n = 0; n < 4; ++n) {
        const int row = wn * 64 + n * 16 + l16;
        const int g = kk * 4 + lhi;
        union { uint4 u; half8 h; } cv;
        cv.u = Bs_g[row * 8 + (g ^ (row & 7))];
        b[n] = cv.h;
      }
#pragma unroll
      for (int m = 0; m < 4; ++m)
#pragma unroll
        for (int n = 0; n < 4; ++n)
          acc[m][n] = __builtin_amdgcn_mfma_f32_16x16x32_f16(a[m], b[n], acc[m][n], 0, 0, 0);
    }
    __syncthreads();
  }

#pragma unroll
  for (int m = 0; m < 4; ++m) {
    const int row0 = bm + wr * 64 + m * 16 + lhi * 4;
#pragma unroll
    for (int n = 0; n < 4; ++n) {
      const int col = bn + wn * 64 + n * 16 + l16;
      const float bv = bias[col];
#pragma unroll
      for (int r = 0; r < 4; ++r) {
        const int row = row0 + r;
        if (row < M) store_c<TC>(C, (size_t)row * N + col, acc[m][n][r] + bv);
      }
    }
  }
}

// ---------------------------------------------------------------------------
// packed f16 fma helper
// ---------------------------------------------------------------------------
__device__ inline uint hfma2u(uint a, uint b, uint c) {
  const __half2 ah = *reinterpret_cast<const __half2*>(&a);
  const __half2 bh = *reinterpret_cast<const __half2*>(&b);
  const __half2 ch = *reinterpret_cast<const __half2*>(&c);
  const __half2 r = __hfma2(ah, bh, ch);
  return *reinterpret_cast<const uint*>(&r);
}

__device__ inline uint pack_wr(float w, uint row) {
  const __half hw = __float2half(w);
  return ((uint)__half_as_ushort(hw) << 16) | row;   // row < 12240 < 2^16
}

// ---------------------------------------------------------------------------
// Fused softmax + location + deformable bilinear sampling, 2 queries / block.
// LDS record = ONE u32 per (sample, corner): (f16 weight << 16) | value-row.
// Layout word idx = (qi<<11)|(s<<5)|(h<<2)|c  -> 16 KB total.
//   phase-1 writes: thread h=tid&7 -> granule index == tid (consecutive, CF)
//   phase-2 reads: per instr 16 consecutive words (h 0..3 x c 0..3), CF,
//                  immediate offset s*128B.
// Phase 2: lane = (qi, h, corner c, dim-quarter d): 1 ds_read_b32 + 1 perm +
//          2 addr VALU + 1 global dwordx4 + 4 pk_fma per sample; corner
//          partials reduced by 2 shfl_xor at the end.
// ---------------------------------------------------------------------------
__global__ __launch_bounds__(256, 8) void sample_kernel(
    const __half* __restrict__ value,     // (LQ, 256) f16
    const __half* __restrict__ logits,    // (LQ, 512) f16
    const __half* __restrict__ off,       // (LQ, 1024) f16
    const float* __restrict__ tempoff,    // (LQ, 4, 4, 2) f32
    const float* __restrict__ refpts,     // (LQ, 4, 2) f32
    __half* __restrict__ msout) {         // (LQ, 256) f16
  const int q0 = blockIdx.x * 2;
  const int tid = threadIdx.x;

  __shared__ __align__(16) uint spk[4096];   // 16 KB packed records
  float* slog = reinterpret_cast<float*>(spk);  // overlay: logits f32[1024]
  __shared__ float sm_m[16], sm_si[16];

  // ---- (a) load logits (2 queries x 512) ----
#pragma unroll
  for (int k = 0; k < 4; ++k) {
    const int s = tid + k * 256;
    slog[s] = __half2float(logits[(size_t)(q0 + (s >> 9)) * 512 + (s & 511)]);
  }
  __syncthreads();

  // ---- (b) per-(query,head) softmax stats: 16 groups x 16 threads ----
  {
    const int g = tid >> 4;
    const int j = tid & 15;
    const float* e = &slog[g * 64];
    float m = fmaxf(fmaxf(e[j], e[j + 16]), fmaxf(e[j + 32], e[j + 48]));
#pragma unroll
    for (int mask = 8; mask >= 1; mask >>= 1) m = fmaxf(m, __shfl_xor(m, mask));
    float s = __expf(e[j] - m) + __expf(e[j + 16] - m) +
              __expf(e[j + 32] - m) + __expf(e[j + 48] - m);
#pragma unroll
    for (int mask = 8; mask >= 1; mask >>= 1) s += __shfl_xor(s, mask);
    if (j == 0) { sm_m[g] = m; sm_si[g] = 1.0f / s; }
  }
  __syncthreads();

  // ---- (c) per-(sample,corner) records -> registers ----
  const float HWF[4] = {2304.f, 576.f, 144.f, 36.f};
  const float RHW[4] = {1.f / 2304.f, 1.f / 576.f, 1.f / 144.f, 1.f / 36.f};
  const int   S0[4]  = {0, 9216, 11520, 12096};
  const int   HWI[4] = {2304, 576, 144, 36};

  uint4 rec[4];
  int   ridx[4];
  const int h1   = tid & 7;
  const int smid = (tid >> 3) & 7;
  const int shi  = (tid >> 6) & 3;

#pragma unroll
  for (int k = 0; k < 4; ++k) {
    const int qi = k & 1;
    const int s  = smid | (shi << 3) | ((k >> 1) << 5);  // true sample id 0..63
    const int i  = h1 * 64 + s;
    const int l  = s >> 4;
    const int f  = (s >> 2) & 3;
    const size_t q = (size_t)(q0 + qi);
    const int g = (qi << 3) | h1;

    const float w = __expf(slog[(qi << 9) + i] - sm_m[g]) * sm_si[g];

    const float2 o  = __half22float2(*reinterpret_cast<const __half2*>(&off[q * 1024 + i * 2]));
    const float2 to = *reinterpret_cast<const float2*>(&tempoff[q * 32 + (l * 4 + f) * 2]);
    const float2 rp = *reinterpret_cast<const float2*>(&refpts[q * 8 + l * 2]);

    const float hw = HWF[l];
    const float x = (to.x + o.x * 0.25f + rp.x) * 4.0f - 0.5f;
    const float y = (to.y + o.y * RHW[l] + rp.y) * hw - 0.5f;

    const float x0f = floorf(x), y0f = floorf(y);
    const float fx = x - x0f, fy = y - y0f;
    const int x0 = (int)x0f, y0 = (int)y0f;
    const int hl = HWI[l];

    const bool xv0 = (x0 >= 0) && (x0 < 4);
    const bool xv1 = (x0 >= -1) && (x0 < 3);
    const bool yv0 = (y0 >= 0) && (y0 < hl);
    const bool yv1 = (y0 >= -1) && (y0 < hl - 1);
    const int xc0 = min(max(x0, 0), 3);
    const int xc1 = min(max(x0 + 1, 0), 3);
    const int yc0 = min(max(y0, 0), hl - 1);
    const int yc1 = min(max(y0 + 1, 0), hl - 1);

    const float w00 = (xv0 && yv0) ? w * (1.f - fx) * (1.f - fy) : 0.f;
    const float w01 = (xv1 && yv0) ? w * fx * (1.f - fy) : 0.f;
    const float w10 = (xv0 && yv1) ? w * (1.f - fx) * fy : 0.f;
    const float w11 = (xv1 && yv1) ? w * fx * fy : 0.f;

    const int base = S0[l];
    rec[k] = make_uint4(pack_wr(w00, (uint)(base + yc0 * 4 + xc0)),
                        pack_wr(w01, (uint)(base + yc0 * 4 + xc1)),
                        pack_wr(w10, (uint)(base + yc1 * 4 + xc0)),
                        pack_wr(w11, (uint)(base + yc1 * 4 + xc1)));
    ridx[k] = (qi << 9) | (s << 3) | h1;   // uint4-granule index
  }
  __syncthreads();   // slog reads complete; records may overlay now

  // ---- (d) write records (consecutive granules per wave: conflict-free) ----
  uint4* spk4 = reinterpret_cast<uint4*>(spk);
#pragma unroll
  for (int k = 0; k < 4; ++k) spk4[ridx[k]] = rec[k];
  __syncthreads();

  // ---- phase 2: gather + packed FMA ----
  const int qi = tid >> 7;          // 0..1
  const int h  = (tid >> 4) & 7;    // 0..7
  const int c  = (tid >> 2) & 3;    // corner
  const int d  = tid & 3;           // dim quarter (16B of the 64B row slice)

  const uint* __restrict__ sp = spk + ((qi << 11) | (h << 2) | c);
  const char* __restrict__ vbase = (const char*)value + h * 64 + d * 16;

  float f0 = 0.f, f1 = 0.f, f2 = 0.f, f3 = 0.f;
  float f4 = 0.f, f5 = 0.f, f6 = 0.f, f7 = 0.f;

#pragma unroll
  for (int l = 0; l < 4; ++l) {
    uint a0 = 0u, a1 = 0u, a2 = 0u, a3 = 0u;
#pragma unroll
    for (int t = 0; t < 16; ++t) {
      const uint pk = sp[(l * 16 + t) << 5];           // ds_read_b32 offset:t*128
      const uint wdup = __builtin_amdgcn_perm(pk, pk, 0x03020302u);  // w|w
      const uint4 v = *reinterpret_cast<const uint4*>(vbase + ((pk & 0xFFFFu) << 9));
      a0 = hfma2u(wdup, v.x, a0);
      a1 = hfma2u(wdup, v.y, a1);
      a2 = hfma2u(wdup, v.z, a2);
      a3 = hfma2u(wdup, v.w, a3);
    }
    const float2 p0 = __half22float2(*reinterpret_cast<const __half2*>(&a0));
    const float2 p1 = __half22float2(*reinterpret_cast<const __half2*>(&a1));
    const float2 p2 = __half22float2(*reinterpret_cast<const __half2*>(&a2));
    const float2 p3 = __half22float2(*reinterpret_cast<const __half2*>(&a3));
    f0 += p0.x; f1 += p0.y; f2 += p1.x; f3 += p1.y;
    f4 += p2.x; f5 += p2.y; f6 += p3.x; f7 += p3.y;
  }

  // reduce across the 4 corner lanes (tid bits 2-3)
#pragma unroll
  for (int mask = 4; mask <= 8; mask <<= 1) {
    f0 += __shfl_xor(f0, mask); f1 += __shfl_xor(f1, mask);
    f2 += __shfl_xor(f2, mask); f3 += __shfl_xor(f3, mask);
    f4 += __shfl_xor(f4, mask); f5 += __shfl_xor(f5, mask);
    f6 += __shfl_xor(f6, mask); f7 += __shfl_xor(f7, mask);
  }

  if (c == 0) {
    const __half2 o0 = __floats2half2_rn(f0, f1);
    const __half2 o1 = __floats2half2_rn(f2, f3);
    const __half2 o2 = __floats2half2_rn(f4, f5);
    const __half2 o3 = __floats2half2_rn(f6, f7);
    uint4 st;
    st.x = *reinterpret_cast<const uint*>(&o0);
    st.y = *reinterpret_cast<const uint*>(&o1);
    st.z = *reinterpret_cast<const uint*>(&o2);
    st.w = *reinterpret_cast<const uint*>(&o3);
    *reinterpret_cast<uint4*>(&msout[(size_t)(q0 + qi) * 256 + h * 32 + d * 8]) = st;
  }
}

// ---------------------------------------------------------------------------
extern "C" void kernel_launch(void* const* d_in, const int* in_sizes, int n_in,
                              void* d_out, int out_size, void* d_ws, size_t ws_size,
                              hipStream_t stream) {
  const float* query   = (const float*)d_in[0];
  const float* refpts  = (const float*)d_in[1];
  const float* tempoff = (const float*)d_in[2];
  const float* inflat  = (const float*)d_in[3];
  const float* W_off  = (const float*)d_in[6];
  const float* b_off  = (const float*)d_in[7];
  const float* W_attn = (const float*)d_in[8];
  const float* b_attn = (const float*)d_in[9];
  const float* W_val  = (const float*)d_in[10];
  const float* b_val  = (const float*)d_in[11];
  const float* W_out  = (const float*)d_in[12];
  const float* b_out  = (const float*)d_in[13];

  char* ws = (char*)d_ws;
  const size_t szQ = (size_t)LQ * 256 * 2;
  __half* qh     = (__half*)ws;                 ws += szQ;
  __half* ifh    = (__half*)ws;                 ws += szQ;
  __half* wT_val = (__half*)ws;                 ws += (size_t)256 * 256 * 2;
  __half* wT_att = (__half*)ws;                 ws += (size_t)512 * 256 * 2;
  __half* wT_off = (__half*)ws;                 ws += (size_t)1024 * 256 * 2;
  __half* wT_out = (__half*)ws;                 ws += (size_t)256 * 256 * 2;
  __half* val_h  = (__half*)ws;                 ws += szQ;
  __half* attn_h = (__half*)ws;                 ws += (size_t)LQ * 512 * 2;
  __half* off_h  = (__half*)ws;                 ws += (size_t)LQ * 1024 * 2;
  __half* ms_h   = (__half*)ws;                 ws += szQ;

  const dim3 blk(256);
  const int n4 = LQ * 256 / 4;

  cvt_f32_f16<<<dim3((n4 + 255) / 256), blk, 0, stream>>>(query, qh, n4);
  cvt_f32_f16<<<dim3((n4 + 255) / 256), blk, 0, stream>>>(inflat, ifh, n4);
  transpose_cvt<<<dim3(8, 8),  blk, 0, stream>>>(W_val,  wT_val, 256);
  transpose_cvt<<<dim3(16, 8), blk, 0, stream>>>(W_attn, wT_att, 512);
  transpose_cvt<<<dim3(32, 8), blk, 0, stream>>>(W_off,  wT_off, 1024);
  transpose_cvt<<<dim3(8, 8),  blk, 0, stream>>>(W_out,  wT_out, 256);

  const int gm = (LQ + 127) / 128;  // 96
  gemm_mfma<__half><<<dim3(2, gm), blk, 0, stream>>>(ifh, wT_val, b_val, val_h, LQ, 256);
  gemm_mfma<__half><<<dim3(4, gm), blk, 0, stream>>>(qh, wT_att, b_attn, attn_h, LQ, 512);
  gemm_mfma<__half><<<dim3(8, gm), blk, 0, stream>>>(qh, wT_off, b_off, off_h, LQ, 1024);

  sample_kernel<<<dim3(LQ / 2), blk, 0, stream>>>(val_h, attn_h, off_h, tempoff, refpts, ms_h);

  gemm_mfma<float><<<dim3(2, gm), blk, 0, stream>>>(ms_h, wT_out, b_out, (float*)d_out, LQ, 256);
}